// Round 2
// baseline (849.165 us; speedup 1.0000x reference)
//
#include <hip/hip_runtime.h>

#define Bn 64
#define Sn 512
#define Hn 1024
#define Tn 67

#define LOG2E 1.4426950408889634f
#define LN2   0.6931471805599453f

// ---------------------------------------------------------------------------
// Kernel 1: em = leaky_relu(hidden, 0.01) @ W + b   (f32, vector ALU)
// grid 512 blocks (64 rows each), 256 threads, K-chunk 32, 4x5 per-thread tile
// ---------------------------------------------------------------------------
__global__ __launch_bounds__(256) void gemm_em(
    const float* __restrict__ hidden, const float* __restrict__ W,
    const float* __restrict__ bias, float* __restrict__ em,
    float* __restrict__ out)
{
    __shared__ __align__(16) float hs[64][36];   // hidden chunk, padded stride
    __shared__ __align__(16) float wt[80][36];   // W chunk transposed [t][k]

    const int tid = threadIdx.x;
    const int tx = tid & 15, ty = tid >> 4;
    const int row0 = blockIdx.x * 64;

    if (blockIdx.x == 0 && tid == 0) out[0] = 0.0f;  // loss accumulator

    float acc[4][5];
#pragma unroll
    for (int u = 0; u < 4; ++u)
#pragma unroll
        for (int v = 0; v < 5; ++v) acc[u][v] = 0.f;

    for (int kc = 0; kc < Hn; kc += 32) {
        // stage hidden chunk: 64 rows x 32 k  (512 float4 loads, 2 per thread)
#pragma unroll
        for (int l = 0; l < 2; ++l) {
            int idx = tid + l * 256;
            int r = idx >> 3, kq = (idx & 7) << 2;
            float4 v = *reinterpret_cast<const float4*>(
                &hidden[(size_t)(row0 + r) * Hn + kc + kq]);
            v.x = v.x > 0.f ? v.x : 0.01f * v.x;
            v.y = v.y > 0.f ? v.y : 0.01f * v.y;
            v.z = v.z > 0.f ? v.z : 0.01f * v.z;
            v.w = v.w > 0.f ? v.w : 0.01f * v.w;
            *reinterpret_cast<float4*>(&hs[r][kq]) = v;
        }
        // stage W chunk transposed: wt[t][k] = W[kc+k][t]
        for (int idx = tid; idx < 32 * Tn; idx += 256) {
            int k = idx / Tn;
            int t = idx - k * Tn;
            wt[t][k] = W[(size_t)(kc + k) * Tn + t];
        }
        __syncthreads();

#pragma unroll
        for (int k0 = 0; k0 < 32; k0 += 4) {
            float4 hv[4], wv[5];
#pragma unroll
            for (int u = 0; u < 4; ++u)
                hv[u] = *reinterpret_cast<float4*>(&hs[ty + 16 * u][k0]);
#pragma unroll
            for (int v = 0; v < 5; ++v)
                wv[v] = *reinterpret_cast<float4*>(&wt[tx + 16 * v][k0]);
#pragma unroll
            for (int u = 0; u < 4; ++u)
#pragma unroll
                for (int v = 0; v < 5; ++v) {
                    acc[u][v] = fmaf(hv[u].x, wv[v].x, acc[u][v]);
                    acc[u][v] = fmaf(hv[u].y, wv[v].y, acc[u][v]);
                    acc[u][v] = fmaf(hv[u].z, wv[v].z, acc[u][v]);
                    acc[u][v] = fmaf(hv[u].w, wv[v].w, acc[u][v]);
                }
        }
        __syncthreads();
    }

#pragma unroll
    for (int v = 0; v < 5; ++v) {
        int c = tx + 16 * v;
        if (c < Tn) {
            float bb = bias[c];
#pragma unroll
            for (int u = 0; u < 4; ++u) {
                int row = row0 + ty + 16 * u;
                em[(size_t)row * Tn + c] = acc[u][v] + bb;
            }
        }
    }
}

// ---------------------------------------------------------------------------
// Kernel 2: per-batch sequential scans.
// blocks 0..63   : CRF forward (logsumexp) + numerator + llh -> atomicAdd loss
// blocks 64..127 : Viterbi forward + backtrace -> tags
// 128 threads (2 waves); thread j < 67 owns output tag j.
// CRF trick: logsumexp_i(s_i + trans_ij) = m + log(sum_i e^{s_i-m} * E_ij),
// E column held in registers -> 67 exps per step (not 67^2), inner = 67 FMA.
// ---------------------------------------------------------------------------
__global__ __launch_bounds__(128) void crf_scan(
    const float* __restrict__ em, const int* __restrict__ labels,
    const int* __restrict__ mask, const float* __restrict__ startT,
    const float* __restrict__ endT, const float* __restrict__ trans,
    float* __restrict__ out)
{
    __shared__ __align__(16) float sArr[68];
    __shared__ __align__(16) float pArr[68];
    __shared__ float redf[128];
    __shared__ int   redi[128];
    __shared__ unsigned char hist[Sn - 1][68];
    __shared__ int tg[Sn];

    const int tid = threadIdx.x;
    const bool isV = blockIdx.x >= 64;
    const int b = blockIdx.x & 63;
    const int j = tid;
    const bool act = j < Tn;
    const int jj = act ? j : 0;
    const float* emb = em + (size_t)b * Sn * Tn;
    const int* maskb = mask + b * Sn;

    if (tid == 67) { sArr[67] = -1e30f; pArr[67] = 0.f; }

    if (!isV) {
        // ---------------- CRF forward ----------------
        float Ecol[68];
#pragma unroll
        for (int i = 0; i < Tn; ++i)
            Ecol[i] = exp2f(trans[i * Tn + jj] * LOG2E);
        Ecol[67] = 0.f;

        float sc = act ? (startT[jj] + emb[jj]) : -1e30f;
        if (act) sArr[j] = sc;
        __syncthreads();

        float em_cur = act ? emb[(size_t)Tn + jj] : 0.f;
        int m_cur = maskb[1];

        for (int t = 1; t < Sn; ++t) {
            float em_nxt = 0.f; int m_nxt = 0;
            if (t + 1 < Sn) {
                em_nxt = act ? emb[(size_t)(t + 1) * Tn + jj] : 0.f;
                m_nxt = maskb[t + 1];
            }
            // max over current scores (broadcast LDS reads)
            float mx = -1e30f;
#pragma unroll
            for (int i4 = 0; i4 < 17; ++i4) {
                float4 v = *reinterpret_cast<float4*>(&sArr[4 * i4]);
                mx = fmaxf(mx, fmaxf(fmaxf(v.x, v.y), fmaxf(v.z, v.w)));
            }
            float p = act ? exp2f((sc - mx) * LOG2E) : 0.f;
            if (act) pArr[j] = p;
            __syncthreads();
            float a0 = 0.f, a1 = 0.f, a2 = 0.f, a3 = 0.f;
#pragma unroll
            for (int i4 = 0; i4 < 17; ++i4) {
                float4 pv = *reinterpret_cast<float4*>(&pArr[4 * i4]);
                a0 = fmaf(pv.x, Ecol[4 * i4 + 0], a0);
                a1 = fmaf(pv.y, Ecol[4 * i4 + 1], a1);
                a2 = fmaf(pv.z, Ecol[4 * i4 + 2], a2);
                a3 = fmaf(pv.w, Ecol[4 * i4 + 3], a3);
            }
            float ssum = (a0 + a1) + (a2 + a3);
            float nxt = mx + log2f(ssum) * LN2 + em_cur;
            if (m_cur) sc = nxt;
            if (act) sArr[j] = sc;
            __syncthreads();
            em_cur = em_nxt; m_cur = m_nxt;
        }

        // denom = logsumexp_j(score_j + end_j)
        float v = act ? (sc + endT[jj]) : -1e30f;
        if (act) sArr[j] = v;
        __syncthreads();
        float mx = -1e30f;
#pragma unroll
        for (int i4 = 0; i4 < 17; ++i4) {
            float4 sv = *reinterpret_cast<float4*>(&sArr[4 * i4]);
            mx = fmaxf(mx, fmaxf(fmaxf(sv.x, sv.y), fmaxf(sv.z, sv.w)));
        }
        float p = act ? exp2f((v - mx) * LOG2E) : 0.f;
        if (act) pArr[j] = p;
        __syncthreads();
        float s0 = 0.f;
#pragma unroll
        for (int i4 = 0; i4 < 17; ++i4) {
            float4 pv = *reinterpret_cast<float4*>(&pArr[4 * i4]);
            s0 += (pv.x + pv.y) + (pv.z + pv.w);
        }
        float denom = mx + log2f(s0) * LN2;

        // numerator partials
        float part = 0.f; int lenp = 0;
        for (int s = tid; s < Sn; s += 128) {
            int ms = maskb[s];
            lenp += ms;
            int ls = labels[b * Sn + s];
            if (s == 0) {
                part += startT[ls] + emb[ls];
            } else if (ms) {
                int lp = labels[b * Sn + s - 1];
                part += trans[lp * Tn + ls] + emb[(size_t)s * Tn + ls];
            }
        }
        redf[tid] = part; redi[tid] = lenp;
        __syncthreads();
        if (tid == 0) {
            float num = 0.f; int len = 0;
            for (int i = 0; i < 128; ++i) { num += redf[i]; len += redi[i]; }
            int last = labels[b * Sn + len - 1];
            num += endT[last];
            float llh = num - denom;
            atomicAdd(out, -llh * (1.0f / (float)Bn));
        }
    } else {
        // ---------------- Viterbi ----------------
        float Tcol[68];
#pragma unroll
        for (int i = 0; i < Tn; ++i) Tcol[i] = trans[i * Tn + jj];
        Tcol[67] = 0.f;

        float sc = act ? (startT[jj] + emb[jj]) : -1e30f;
        if (act) sArr[j] = sc;
        __syncthreads();

        float em_cur = act ? emb[(size_t)Tn + jj] : 0.f;
        int m_cur = maskb[1];

        for (int t = 1; t < Sn; ++t) {
            float em_nxt = 0.f; int m_nxt = 0;
            if (t + 1 < Sn) {
                em_nxt = act ? emb[(size_t)(t + 1) * Tn + jj] : 0.f;
                m_nxt = maskb[t + 1];
            }
            float best = -1e30f; int bi = 0;
#pragma unroll
            for (int i4 = 0; i4 < 17; ++i4) {
                float4 sv = *reinterpret_cast<float4*>(&sArr[4 * i4]);
                float c0 = sv.x + Tcol[4 * i4 + 0];
                if (c0 > best) { best = c0; bi = 4 * i4 + 0; }
                float c1 = sv.y + Tcol[4 * i4 + 1];
                if (c1 > best) { best = c1; bi = 4 * i4 + 1; }
                float c2 = sv.z + Tcol[4 * i4 + 2];
                if (c2 > best) { best = c2; bi = 4 * i4 + 2; }
                float c3 = sv.w + Tcol[4 * i4 + 3];
                if (c3 > best) { best = c3; bi = 4 * i4 + 3; }
            }
            float nxt = best + em_cur;
            int idx = m_cur ? bi : j;   // !mask -> identity
            if (m_cur) sc = nxt;
            __syncthreads();            // all done reading sArr
            if (act) { hist[t - 1][j] = (unsigned char)idx; sArr[j] = sc; }
            __syncthreads();
            em_cur = em_nxt; m_cur = m_nxt;
        }

        // final argmax (first-index tie-break) + serial backtrace
        float v = act ? (sc + endT[jj]) : -1e30f;
        if (act) pArr[j] = v;
        __syncthreads();
        if (tid == 0) {
            float best = -1e30f; int bi = 0;
            for (int i = 0; i < Tn; ++i) {
                float c = pArr[i];
                if (c > best) { best = c; bi = i; }
            }
            int carry = bi;
            tg[Sn - 1] = carry;
            for (int k = Sn - 2; k >= 0; --k) {
                carry = hist[k][carry];
                tg[k] = carry;
            }
        }
        __syncthreads();
        float* tagsOut = out + 1 + b * Sn;
        for (int s = tid; s < Sn; s += 128)
            tagsOut[s] = maskb[s] ? (float)tg[s] : 0.f;
    }
}

extern "C" void kernel_launch(void* const* d_in, const int* in_sizes, int n_in,
                              void* d_out, int out_size, void* d_ws, size_t ws_size,
                              hipStream_t stream) {
    const float* hidden = (const float*)d_in[0];
    const int*   labels = (const int*)d_in[1];
    const int*   maskp  = (const int*)d_in[2];
    const float* W      = (const float*)d_in[3];
    const float* bias   = (const float*)d_in[4];
    const float* startT = (const float*)d_in[5];
    const float* endT   = (const float*)d_in[6];
    const float* trans  = (const float*)d_in[7];
    float* out = (float*)d_out;
    float* em  = out + 1 + (size_t)Bn * Sn;   // em region of output

    hipLaunchKernelGGL(gemm_em, dim3((Bn * Sn) / 64), dim3(256), 0, stream,
                       hidden, W, bias, em, out);
    hipLaunchKernelGGL(crf_scan, dim3(128), dim3(128), 0, stream,
                       em, labels, maskp, startT, endT, trans, out);
}

// Round 5
// 712.726 us; speedup vs baseline: 1.1914x; 1.1914x over previous
//
#include <hip/hip_runtime.h>

#define Bn 64
#define Sn 512
#define Hn 1024
#define Tn 67

#define LOG2E 1.4426950408889634f
#define LN2   0.6931471805599453f

// ---------------------------------------------------------------------------
// Kernel 1: em = leaky_relu(hidden, 0.01) @ W + b   (f32, vector ALU)
// UNCHANGED from round 2 (tags depend on em rounding; it passed).
// ---------------------------------------------------------------------------
__global__ __launch_bounds__(256) void gemm_em(
    const float* __restrict__ hidden, const float* __restrict__ W,
    const float* __restrict__ bias, float* __restrict__ em,
    float* __restrict__ out)
{
    __shared__ __align__(16) float hs[64][36];
    __shared__ __align__(16) float wt[80][36];

    const int tid = threadIdx.x;
    const int tx = tid & 15, ty = tid >> 4;
    const int row0 = blockIdx.x * 64;

    if (blockIdx.x == 0 && tid == 0) out[0] = 0.0f;  // loss accumulator

    float acc[4][5];
#pragma unroll
    for (int u = 0; u < 4; ++u)
#pragma unroll
        for (int v = 0; v < 5; ++v) acc[u][v] = 0.f;

    for (int kc = 0; kc < Hn; kc += 32) {
#pragma unroll
        for (int l = 0; l < 2; ++l) {
            int idx = tid + l * 256;
            int r = idx >> 3, kq = (idx & 7) << 2;
            float4 v = *reinterpret_cast<const float4*>(
                &hidden[(size_t)(row0 + r) * Hn + kc + kq]);
            v.x = v.x > 0.f ? v.x : 0.01f * v.x;
            v.y = v.y > 0.f ? v.y : 0.01f * v.y;
            v.z = v.z > 0.f ? v.z : 0.01f * v.z;
            v.w = v.w > 0.f ? v.w : 0.01f * v.w;
            *reinterpret_cast<float4*>(&hs[r][kq]) = v;
        }
        for (int idx = tid; idx < 32 * Tn; idx += 256) {
            int k = idx / Tn;
            int t = idx - k * Tn;
            wt[t][k] = W[(size_t)(kc + k) * Tn + t];
        }
        __syncthreads();

#pragma unroll
        for (int k0 = 0; k0 < 32; k0 += 4) {
            float4 hv[4], wv[5];
#pragma unroll
            for (int u = 0; u < 4; ++u)
                hv[u] = *reinterpret_cast<float4*>(&hs[ty + 16 * u][k0]);
#pragma unroll
            for (int v = 0; v < 5; ++v)
                wv[v] = *reinterpret_cast<float4*>(&wt[tx + 16 * v][k0]);
#pragma unroll
            for (int u = 0; u < 4; ++u)
#pragma unroll
                for (int v = 0; v < 5; ++v) {
                    acc[u][v] = fmaf(hv[u].x, wv[v].x, acc[u][v]);
                    acc[u][v] = fmaf(hv[u].y, wv[v].y, acc[u][v]);
                    acc[u][v] = fmaf(hv[u].z, wv[v].z, acc[u][v]);
                    acc[u][v] = fmaf(hv[u].w, wv[v].w, acc[u][v]);
                }
        }
        __syncthreads();
    }

#pragma unroll
    for (int v = 0; v < 5; ++v) {
        int c = tx + 16 * v;
        if (c < Tn) {
            float bb = bias[c];
#pragma unroll
            for (int u = 0; u < 4; ++u) {
                int row = row0 + ty + 16 * u;
                em[(size_t)row * Tn + c] = acc[u][v] + bb;
            }
        }
    }
}

// ---------------------------------------------------------------------------
// Kernel 2: fused per-batch CRF + Viterbi scan. 64 blocks x 256 threads.
// wave0: CRF states 0-63   wave1: CRF states 64-66
// wave2: Vit states 0-63   wave3: Vit states 64-66
// One __syncthreads per step (double-buffered LDS state).
// CRF: p_i = exp(sc_i - M̂) stored directly; M̂ = lagged state-0 score carried
//      in slot [68], M-used-for-p in slot [69]; slot [67] is a zero pad that
//      Ecol[67]=0 nullifies in the matvec.
// Viterbi: pairwise tree max/argmax, left-preference on strict '>' keeps
//      first-index tie-break; value arithmetic identical order to reference.
// em staged to LDS in 32-step double-buffered chunks (CRF waves stage).
// ---------------------------------------------------------------------------
__global__ __launch_bounds__(256) void crf_scan2(
    const float* __restrict__ em, const int* __restrict__ labels,
    const int* __restrict__ mask, const float* __restrict__ startT,
    const float* __restrict__ endT, const float* __restrict__ trans,
    float* __restrict__ out)
{
    __shared__ __align__(16) float pbuf[2][72];
    __shared__ __align__(16) float vbuf[2][72];
    __shared__ __align__(16) float em_lds[2][32 * Tn];
    __shared__ int mask_lds[Sn];
    __shared__ unsigned char hist[Sn - 1][68];
    __shared__ int tg[Sn];
    __shared__ float redf[256];
    __shared__ int redi[256];

    const int tid = threadIdx.x;
    const int wid = tid >> 6;
    const int lane = tid & 63;
    const int b = blockIdx.x;
    const bool isCRF = wid < 2;
    const bool hiw = (wid & 1);
    const int st = hiw ? (64 + (lane < 3 ? lane : 2)) : lane;
    const bool active = (!hiw) || (lane < 3);
    const float* emg = em + (size_t)b * Sn * Tn;

    // ---- prologue: stage chunk 0, mask, init pads ----
    for (int i = tid; i < 32 * Tn; i += 256) em_lds[0][i] = emg[i];
    for (int i = tid; i < Sn; i += 256) mask_lds[i] = mask[b * Sn + i];
    if (tid == 0) {
        pbuf[0][67] = 0.f; pbuf[1][67] = 0.f;
        vbuf[0][67] = -1e30f; vbuf[1][67] = -1e30f;
    }
    __syncthreads();

    float sc = startT[st] + em_lds[0][st];
    if (isCRF) { if (active) pbuf[1][st] = sc; }
    else       { if (active) vbuf[0][st] = sc; }
    __syncthreads();
    if (isCRF) {
        float M0 = pbuf[1][0];
        float p = exp2f((sc - M0) * LOG2E);
        if (active) pbuf[0][st] = p;
        if (tid == 0) { pbuf[0][68] = sc; pbuf[0][69] = M0; }
    }
    __syncthreads();

    int bufc = 0;
    if (isCRF) {
        // -------- CRF loop --------
        float Ecol[68];
#pragma unroll
        for (int i = 0; i < Tn; ++i) Ecol[i] = exp2f(trans[i * Tn + st] * LOG2E);
        Ecol[67] = 0.f;

        for (int t = 1; t < Sn; ++t) {
            if ((t & 31) == 1) {                 // stage next em chunk
                int k = (t >> 5) + 1;
                if (k < 16) {
                    const float* src = emg + (size_t)k * 32 * Tn;
                    float* dst = em_lds[k & 1];
                    for (int i = tid; i < 32 * Tn; i += 128) dst[i] = src[i];
                }
            }
            const float* row = em_lds[(t >> 5) & 1] + (t & 31) * Tn;
            float em_t = row[st];
            int m = mask_lds[t];
            float M_used = pbuf[bufc][69];
            float sc0p   = pbuf[bufc][68];
            const float4* P = (const float4*)&pbuf[bufc][0];
            float a0 = 0.f, a1 = 0.f, a2 = 0.f, a3 = 0.f;
#pragma unroll
            for (int q = 0; q < 17; ++q) {
                float4 pv = P[q];
                a0 = fmaf(pv.x, Ecol[4 * q + 0], a0);
                a1 = fmaf(pv.y, Ecol[4 * q + 1], a1);
                a2 = fmaf(pv.z, Ecol[4 * q + 2], a2);
                a3 = fmaf(pv.w, Ecol[4 * q + 3], a3);
            }
            float aa = (a0 + a1) + (a2 + a3);
            float nxt = M_used + log2f(aa) * LN2 + em_t;
            if (m) sc = nxt;
            float Mn = sc0p;
            float p = exp2f((sc - Mn) * LOG2E);
            int nb = bufc ^ 1;
            if (active) pbuf[nb][st] = p;
            if (tid == 0) { pbuf[nb][68] = sc; pbuf[nb][69] = Mn; }
            __syncthreads();
            bufc = nb;
        }
    } else {
        // -------- Viterbi loop --------
        float Tcol[68];
#pragma unroll
        for (int i = 0; i < Tn; ++i) Tcol[i] = trans[i * Tn + st];
        Tcol[67] = 0.f;

        for (int t = 1; t < Sn; ++t) {
            const float* row = em_lds[(t >> 5) & 1] + (t & 31) * Tn;
            float em_t = row[st];
            int m = mask_lds[t];
            const float4* Vp = (const float4*)&vbuf[bufc][0];
            float bvv[34]; int bx[34];
#pragma unroll
            for (int q = 0; q < 17; ++q) {
                float4 v = Vp[q];
                float c0 = v.x + Tcol[4 * q + 0];
                float c1 = v.y + Tcol[4 * q + 1];
                float c2 = v.z + Tcol[4 * q + 2];
                float c3 = v.w + Tcol[4 * q + 3];
                bool r0 = c1 > c0;
                bvv[2 * q]     = r0 ? c1 : c0;
                bx[2 * q]      = r0 ? 4 * q + 1 : 4 * q + 0;
                bool r1 = c3 > c2;
                bvv[2 * q + 1] = r1 ? c3 : c2;
                bx[2 * q + 1]  = r1 ? 4 * q + 3 : 4 * q + 2;
            }
            // 34 -> 17
#pragma unroll
            for (int q = 0; q < 17; ++q) {
                bool r = bvv[2 * q + 1] > bvv[2 * q];
                bvv[q] = r ? bvv[2 * q + 1] : bvv[2 * q];
                bx[q]  = r ? bx[2 * q + 1]  : bx[2 * q];
            }
            // 17 -> 9
#pragma unroll
            for (int q = 0; q < 8; ++q) {
                bool r = bvv[2 * q + 1] > bvv[2 * q];
                bvv[q] = r ? bvv[2 * q + 1] : bvv[2 * q];
                bx[q]  = r ? bx[2 * q + 1]  : bx[2 * q];
            }
            bvv[8] = bvv[16]; bx[8] = bx[16];
            // 9 -> 5
#pragma unroll
            for (int q = 0; q < 4; ++q) {
                bool r = bvv[2 * q + 1] > bvv[2 * q];
                bvv[q] = r ? bvv[2 * q + 1] : bvv[2 * q];
                bx[q]  = r ? bx[2 * q + 1]  : bx[2 * q];
            }
            bvv[4] = bvv[8]; bx[4] = bx[8];
            // 5 -> 3
#pragma unroll
            for (int q = 0; q < 2; ++q) {
                bool r = bvv[2 * q + 1] > bvv[2 * q];
                bvv[q] = r ? bvv[2 * q + 1] : bvv[2 * q];
                bx[q]  = r ? bx[2 * q + 1]  : bx[2 * q];
            }
            bvv[2] = bvv[4]; bx[2] = bx[4];
            // 3 -> 1
            { bool r = bvv[1] > bvv[0]; bvv[0] = r ? bvv[1] : bvv[0]; bx[0] = r ? bx[1] : bx[0]; }
            { bool r = bvv[2] > bvv[0]; bvv[0] = r ? bvv[2] : bvv[0]; bx[0] = r ? bx[2] : bx[0]; }

            float nv = bvv[0] + em_t;
            int idx = m ? bx[0] : st;
            if (m) sc = nv;
            int nb = bufc ^ 1;
            if (active) {
                hist[t - 1][st] = (unsigned char)idx;
                vbuf[nb][st] = sc;
            }
            __syncthreads();
            bufc = nb;
        }
    }

    // ---- epilogue ----
    if (isCRF) { if (active) pbuf[0][st] = sc + endT[st]; }
    else       { if (active) vbuf[0][st] = sc + endT[st]; }
    __syncthreads();

    // numerator partials (all threads)
    float part = 0.f; int lenp = 0;
    for (int s = tid; s < Sn; s += 256) {
        int ms = mask_lds[s];
        lenp += ms;
        int ls = labels[b * Sn + s];
        if (s == 0) {
            part += startT[ls] + emg[ls];
        } else if (ms) {
            int lp = labels[b * Sn + s - 1];
            part += trans[lp * Tn + ls] + emg[(size_t)s * Tn + ls];
        }
    }
    redf[tid] = part; redi[tid] = lenp;
    __syncthreads();

    if (tid == 0) {
        float mx = -1e30f;
        for (int i = 0; i < Tn; ++i) mx = fmaxf(mx, pbuf[0][i]);
        float ss = 0.f;
        for (int i = 0; i < Tn; ++i) ss += exp2f((pbuf[0][i] - mx) * LOG2E);
        float denom = mx + log2f(ss) * LN2;
        float num = 0.f; int len = 0;
        for (int i = 0; i < 256; ++i) { num += redf[i]; len += redi[i]; }
        int last = labels[b * Sn + len - 1];
        num += endT[last];
        atomicAdd(out, -(num - denom) * (1.0f / (float)Bn));
    }
    if (tid == 128) {
        float best = -1e30f; int bi = 0;
        for (int i = 0; i < Tn; ++i) {
            float c = vbuf[0][i];
            if (c > best) { best = c; bi = i; }
        }
        int carry = bi;
        tg[Sn - 1] = carry;
        for (int k = Sn - 2; k >= 0; --k) {
            carry = hist[k][carry];
            tg[k] = carry;
        }
    }
    __syncthreads();

    float* tagsOut = out + 1 + b * Sn;
    for (int s = tid; s < Sn; s += 256)
        tagsOut[s] = mask_lds[s] ? (float)tg[s] : 0.f;
}

extern "C" void kernel_launch(void* const* d_in, const int* in_sizes, int n_in,
                              void* d_out, int out_size, void* d_ws, size_t ws_size,
                              hipStream_t stream) {
    const float* hidden = (const float*)d_in[0];
    const int*   labels = (const int*)d_in[1];
    const int*   maskp  = (const int*)d_in[2];
    const float* W      = (const float*)d_in[3];
    const float* bias   = (const float*)d_in[4];
    const float* startT = (const float*)d_in[5];
    const float* endT   = (const float*)d_in[6];
    const float* trans  = (const float*)d_in[7];
    float* out = (float*)d_out;
    float* em  = out + 1 + (size_t)Bn * Sn;   // em region of output

    hipLaunchKernelGGL(gemm_em, dim3((Bn * Sn) / 64), dim3(256), 0, stream,
                       hidden, W, bias, em, out);
    hipLaunchKernelGGL(crf_scan2, dim3(Bn), dim3(256), 0, stream,
                       em, labels, maskp, startT, endT, trans, out);
}